// Round 9
// baseline (119.698 us; speedup 1.0000x reference)
//
#include <hip/hip_runtime.h>
#include <hip/hip_bf16.h>

typedef _Float16 f16;
typedef _Float16 f16x8 __attribute__((ext_vector_type(8)));
typedef _Float16 f16x4 __attribute__((ext_vector_type(4)));
typedef float f32x4 __attribute__((ext_vector_type(4)));
typedef int i32x4 __attribute__((ext_vector_type(4)));

#define LDS_LOAD16(gptr, lptr)                                                             \
  __builtin_amdgcn_global_load_lds(                                                        \
      (const __attribute__((address_space(1))) unsigned int*)(gptr),                       \
      (__attribute__((address_space(3))) unsigned int*)(lptr), 16, 0, 0)

// 0.125 (1/sqrt(HD)) * log2(e): folded into Q so QK^T yields log2e-scaled scores
#define ALPHA 0.18033688f
// masked score: reference sets score=1e-9 (log2e domain)
#define MASKVAL 1.44269504e-9f

// ---------------------------------------------------------------------------
// fused fp32 -> fp16 conversion for x + 4 weight matrices
// ---------------------------------------------------------------------------
__global__ __launch_bounds__(256) void conv_all(const float* __restrict__ x,
                                                const float* __restrict__ Wq,
                                                const float* __restrict__ Wk,
                                                const float* __restrict__ Wv,
                                                const float* __restrict__ Wo,
                                                f16* __restrict__ xh, f16* __restrict__ wqh,
                                                f16* __restrict__ wkh, f16* __restrict__ wvh,
                                                f16* __restrict__ woh) {
  int i = blockIdx.x * 256 + threadIdx.x;
  const float* src;
  f16* dst;
  int off;
  if (i < 524288) {
    src = x; dst = xh; off = i;
  } else {
    int j = i - 524288;
    int w = j >> 17;
    off = j & 131071;
    src = (w == 0) ? Wq : (w == 1) ? Wk : (w == 2) ? Wv : Wo;
    dst = (w == 0) ? wqh : (w == 1) ? wkh : (w == 2) ? wvh : woh;
  }
  const float4* s4 = (const float4*)src;
  float4 a = s4[2 * off];
  float4 b = s4[2 * off + 1];
  f16x8 o = {(f16)a.x, (f16)a.y, (f16)a.z, (f16)a.w,
             (f16)b.x, (f16)b.y, (f16)b.z, (f16)b.w};
  *(f16x8*)(dst + (size_t)off * 8) = o;
}

// ---------------------------------------------------------------------------
// Fused QKV projection: z=0 -> Q (scaled by ALPHA), z=1 -> K, z=2 -> V^T.
// 2-phase pipeline: stage(t+1) issued BEFORE compute(t); counted vmcnt(4)
// drains only tile t's loads; double-buffered LDS (32 KB, 3 blocks/CU).
// ---------------------------------------------------------------------------
__global__ __launch_bounds__(256) void gemm_qkv(const f16* __restrict__ A,
                                                const f16* __restrict__ W0,
                                                const f16* __restrict__ W1,
                                                const f16* __restrict__ W2,
                                                const float* __restrict__ b0,
                                                const float* __restrict__ b1,
                                                const float* __restrict__ b2,
                                                f16* __restrict__ qo, f16* __restrict__ ko,
                                                f16* __restrict__ vo) {
  constexpr int K = 1024, BM = 128, BK = 32, NKT = K / BK;
  __shared__ f16 aT[2][BM * BK];
  __shared__ f16 bT[2][BM * BK];
  const int z = blockIdx.z;
  const f16* Bw = (z == 0) ? W0 : (z == 1) ? W1 : W2;
  const float* bias = (z == 0) ? b0 : (z == 1) ? b1 : b2;
  const int tid = threadIdx.x, wid = tid >> 6, lane = tid & 63;
  const int mb = blockIdx.y * BM, nb = blockIdx.x * BM;
  const int wr = wid >> 1, wc = wid & 1;
  const int lr = lane & 15, hi = lane >> 4;

  f32x4 acc[4][4] = {};

  const int r0 = tid >> 2, s0 = tid & 3;
  const int ci1 = 256 + tid, r1 = ci1 >> 2, s1 = ci1 & 3;

#define STAGE_QKV(bb, kt)                                                                   \
  do {                                                                                      \
    const int kb_ = (kt) * BK;                                                              \
    LDS_LOAD16(A + (size_t)(mb + r0) * K + kb_ + s0 * 8, (char*)aT[bb] + wid * 1024);       \
    LDS_LOAD16(Bw + (size_t)(nb + r0) * K + kb_ + s0 * 8, (char*)bT[bb] + wid * 1024);      \
    LDS_LOAD16(A + (size_t)(mb + r1) * K + kb_ + s1 * 8, (char*)aT[bb] + 4096 + wid * 1024);\
    LDS_LOAD16(Bw + (size_t)(nb + r1) * K + kb_ + s1 * 8, (char*)bT[bb] + 4096 + wid * 1024);\
  } while (0)

  STAGE_QKV(0, 0);
  for (int kt = 0; kt < NKT; ++kt) {
    const int p = kt & 1;
    if (kt + 1 < NKT) {
      STAGE_QKV(p ^ 1, kt + 1);
      asm volatile("s_waitcnt vmcnt(4)" ::: "memory");
    } else {
      asm volatile("s_waitcnt vmcnt(0)" ::: "memory");
    }
    __builtin_amdgcn_s_barrier();

    f16x8 af[4], bf[4];
#pragma unroll
    for (int i = 0; i < 4; ++i) af[i] = *(const f16x8*)&aT[p][(wr * 64 + i * 16 + lr) * BK + hi * 8];
#pragma unroll
    for (int j = 0; j < 4; ++j) bf[j] = *(const f16x8*)&bT[p][(wc * 64 + j * 16 + lr) * BK + hi * 8];
    __builtin_amdgcn_s_setprio(1);
#pragma unroll
    for (int i = 0; i < 4; ++i)
#pragma unroll
      for (int j = 0; j < 4; ++j)
        acc[i][j] = __builtin_amdgcn_mfma_f32_16x16x32_f16(af[i], bf[j], acc[i][j], 0, 0, 0);
    __builtin_amdgcn_s_setprio(0);
    __builtin_amdgcn_s_barrier();
  }

  const float scale = (z == 0) ? ALPHA : 1.0f;
#pragma unroll
  for (int i = 0; i < 4; ++i) {
#pragma unroll
    for (int j = 0; j < 4; ++j) {
      const int row = mb + wr * 64 + i * 16 + hi * 4;
      const int col = nb + wc * 64 + j * 16 + lr;
      const float bv = bias[col];
      const int hh = col >> 6, dd = col & 63;
      if (z == 2) {
        const int bb = row >> 11, l = row & 2047;
        f16x4 v4;
#pragma unroll
        for (int r = 0; r < 4; ++r) v4[r] = (f16)(acc[i][j][r] + bv);
        *(f16x4*)(vo + ((((size_t)bb * 16 + hh) * 64 + dd) * 2048 + l)) = v4;
      } else {
        f16* o = z ? ko : qo;
#pragma unroll
        for (int r = 0; r < 4; ++r) {
          const int m2 = row + r;
          const int bb = m2 >> 11, l = m2 & 2047;
          o[((((size_t)bb * 16 + hh) * 2048 + l) * 64) + dd] = (f16)((acc[i][j][r] + bv) * scale);
        }
      }
    }
  }
}

// ---------------------------------------------------------------------------
// Output projection: 64(M)x128(N) tile, 4 waves of 32x64, 2-phase pipeline.
// ---------------------------------------------------------------------------
__global__ __launch_bounds__(256) void gemm_o(const f16* __restrict__ A,
                                              const f16* __restrict__ W,
                                              const float* __restrict__ bias,
                                              float* __restrict__ out) {
  constexpr int K = 1024, N = 1024, BK = 32, NKT = K / BK;
  __shared__ f16 aT[2][64 * BK];
  __shared__ f16 bT[2][128 * BK];
  const int tid = threadIdx.x, wid = tid >> 6, lane = tid & 63;
  const int lr = lane & 15, hi = lane >> 4;
  const int mb = blockIdx.y * 64, nb = blockIdx.x * 128;
  const int wr = wid >> 1, wc = wid & 1;
  f32x4 acc[2][4] = {};
  const int ra = tid >> 2, sa = tid & 3;
  const int rb1 = (256 + tid) >> 2, sb1 = (256 + tid) & 3;

#define STAGE_O(bb, kt)                                                                     \
  do {                                                                                      \
    const int kb_ = (kt) * BK;                                                              \
    LDS_LOAD16(A + (size_t)(mb + ra) * K + kb_ + sa * 8, (char*)aT[bb] + wid * 1024);       \
    LDS_LOAD16(W + (size_t)(nb + ra) * K + kb_ + sa * 8, (char*)bT[bb] + wid * 1024);       \
    LDS_LOAD16(W + (size_t)(nb + rb1) * K + kb_ + sb1 * 8, (char*)bT[bb] + 4096 + wid * 1024);\
  } while (0)

  STAGE_O(0, 0);
  for (int kt = 0; kt < NKT; ++kt) {
    const int p = kt & 1;
    if (kt + 1 < NKT) {
      STAGE_O(p ^ 1, kt + 1);
      asm volatile("s_waitcnt vmcnt(3)" ::: "memory");
    } else {
      asm volatile("s_waitcnt vmcnt(0)" ::: "memory");
    }
    __builtin_amdgcn_s_barrier();
    f16x8 af[2], bf[4];
#pragma unroll
    for (int i = 0; i < 2; ++i) af[i] = *(const f16x8*)&aT[p][(wr * 32 + i * 16 + lr) * BK + hi * 8];
#pragma unroll
    for (int j = 0; j < 4; ++j) bf[j] = *(const f16x8*)&bT[p][(wc * 64 + j * 16 + lr) * BK + hi * 8];
    __builtin_amdgcn_s_setprio(1);
#pragma unroll
    for (int i = 0; i < 2; ++i)
#pragma unroll
      for (int j = 0; j < 4; ++j)
        acc[i][j] = __builtin_amdgcn_mfma_f32_16x16x32_f16(af[i], bf[j], acc[i][j], 0, 0, 0);
    __builtin_amdgcn_s_setprio(0);
    __builtin_amdgcn_s_barrier();
  }
#pragma unroll
  for (int i = 0; i < 2; ++i)
#pragma unroll
    for (int j = 0; j < 4; ++j) {
      const int col = nb + wc * 64 + j * 16 + lr;
      const float bv = bias[col];
#pragma unroll
      for (int r = 0; r < 4; ++r)
        out[(size_t)(mb + wr * 32 + i * 16 + hi * 4 + r) * N + col] = acc[i][j][r] + bv;
    }
}

// ---------------------------------------------------------------------------
// Flash attention v3.1: 2-wave blocks, 32 q/wave, KV tiles of 64, dbuf
// staging, ONE barrier/tile.  P never touches LDS (cvt_pkrtz pairs +
// v_permlane32_swap_b32 + ds_swizzle(xor16) + cndmask transpose).  Mask
// scanned once per kernel (all-ones fast path).  Row-sums via ones-MFMA.
// p = exp2(score*log2e); Q pre-scaled by ALPHA.
// ---------------------------------------------------------------------------
__global__ __launch_bounds__(128, 2) void attn2w(const f16* __restrict__ Qh,
                                                 const f16* __restrict__ Kh,
                                                 const f16* __restrict__ Vt,
                                                 const int* __restrict__ mask,
                                                 f16* __restrict__ Oa) {
  constexpr int L = 2048, HD = 64, H = 16, NT = L / 64;
  // [parity][ K(8KB) | V(8KB) ] = 32 KB total
  __shared__ __align__(16) char ldsb[32768];

  const int tid = threadIdx.x, w = tid >> 6, lane = tid & 63;
  const int lr = lane & 15, hi = lane >> 4;
  const int sw = lr & 7;
  const bool oddhi = (hi & 1) != 0;

  // XCD-bijective remap: bid bits [2:0]=xcd, [7:3]=qb, [9:8]=head-in-xcd
  const int bid = blockIdx.x;  // 1024 blocks
  const int head = (bid & 7) * 4 + (bid >> 8);
  const int qb = (bid >> 3) & 31;
  const int b = head >> 4, h = head & 15;
  const int qr0 = qb * 64 + w * 32;

  const f16* Qb = Qh + (size_t)head * L * HD;
  const f16* Kb = Kh + (size_t)head * L * HD;
  const f16* Vb = Vt + (size_t)head * HD * L;
  const int* mrow = mask + b * L;

  // whole-row mask scan (wave-uniform fast path; mask is 0/1 ints)
  int mred = 1;
  {
    const int4* m4 = (const int4*)mrow;
#pragma unroll
    for (int j = 0; j < 8; ++j) {
      int4 v = m4[lane + j * 64];
      mred &= v.x & v.y & v.z & v.w;
    }
  }
  const bool allm = __all(mred == 1);

  // staging: each wave stages rows [w*32, w*32+32) of K and of V^T.
  const int srow = lane >> 3;
  const int schk = (lane & 7) ^ srow;

#define STAGE2W(bb, kt)                                                                     \
  _Pragma("unroll") for (int c = 0; c < 4; ++c) {                                           \
    LDS_LOAD16(Kb + (size_t)((kt) * 64 + w * 32 + c * 8 + srow) * HD + schk * 8,            \
               ldsb + (bb) * 16384 + w * 4096 + c * 1024);                                  \
    LDS_LOAD16(Vb + (size_t)(w * 32 + c * 8 + srow) * L + (kt) * 64 + schk * 8,             \
               ldsb + (bb) * 16384 + 8192 + w * 4096 + c * 1024);                           \
  }

  // per-lane LDS read bases (k2=0 / k2=1 chunk swizzle), all else via imms
  const char* kbase0 = ldsb + lr * 128 + ((hi ^ sw) * 16);
  const char* kbase1 = ldsb + lr * 128 + (((4 + hi) ^ sw) * 16);

  // Q fragments (B-operand), resident for the whole kernel
  f16x8 qf[2][2];
#pragma unroll
  for (int qg = 0; qg < 2; ++qg)
#pragma unroll
    for (int k2 = 0; k2 < 2; ++k2)
      qf[qg][k2] = *(const f16x8*)&Qb[(size_t)(qr0 + qg * 16 + lr) * HD + k2 * 32 + hi * 8];

  f32x4 oacc[2][4] = {};
  f32x4 lacc[2] = {};
  const f32x4 zacc = {0.f, 0.f, 0.f, 0.f};
  const f16x8 ones = {1, 1, 1, 1, 1, 1, 1, 1};

  int4 mvA[4], mvB[4];
  if (!allm) {
#pragma unroll
    for (int nf = 0; nf < 4; ++nf) mvA[nf] = *(const int4*)&mrow[nf * 16 + hi * 4];
  }
  STAGE2W(0, 0);

#define ATTN_ITER(kt, P, MVR, MVL)                                                          \
  do {                                                                                      \
    asm volatile("s_waitcnt vmcnt(0)" ::: "memory");                                        \
    __builtin_amdgcn_s_barrier();                                                           \
    if ((kt) + 1 < NT) {                                                                    \
      if (!allm) {                                                                          \
        _Pragma("unroll") for (int nf = 0; nf < 4; ++nf)                                    \
            MVL[nf] = *(const int4*)&mrow[((kt) + 1) * 64 + nf * 16 + hi * 4];              \
      }                                                                                     \
      STAGE2W((P) ^ 1, (kt) + 1);                                                           \
    }                                                                                       \
    f16x8 kf[4][2];                                                                         \
    _Pragma("unroll") for (int nf = 0; nf < 4; ++nf) {                                      \
      kf[nf][0] = *(const f16x8*)(kbase0 + (P) * 16384 + nf * 2048);                        \
      kf[nf][1] = *(const f16x8*)(kbase1 + (P) * 16384 + nf * 2048);                        \
    }                                                                                       \
    f32x4 s[2][4];                                                                          \
    __builtin_amdgcn_s_setprio(1);                                                          \
    _Pragma("unroll") for (int qg = 0; qg < 2; ++qg)                                        \
        _Pragma("unroll") for (int nf = 0; nf < 4; ++nf) {                                  \
      f32x4 z = __builtin_amdgcn_mfma_f32_16x16x32_f16(kf[nf][0], qf[qg][0], zacc, 0, 0, 0);\
      s[qg][nf] = __builtin_amdgcn_mfma_f32_16x16x32_f16(kf[nf][1], qf[qg][1], z, 0, 0, 0); \
    }                                                                                       \
    __builtin_amdgcn_s_setprio(0);                                                          \
    f16x8 pf[2][2];                                                                         \
    _Pragma("unroll") for (int qg = 0; qg < 2; ++qg) {                                      \
      int wpk[4][2];                                                                        \
      _Pragma("unroll") for (int nf = 0; nf < 4; ++nf) {                                    \
        float p0, p1, p2, p3;                                                               \
        if (allm) {                                                                         \
          p0 = __builtin_amdgcn_exp2f(s[qg][nf][0]);                                        \
          p1 = __builtin_amdgcn_exp2f(s[qg][nf][1]);                                        \
          p2 = __builtin_amdgcn_exp2f(s[qg][nf][2]);                                        \
          p3 = __builtin_amdgcn_exp2f(s[qg][nf][3]);                                        \
        } else {                                                                            \
          p0 = __builtin_amdgcn_exp2f(MVR[nf].x ? s[qg][nf][0] : MASKVAL);                  \
          p1 = __builtin_amdgcn_exp2f(MVR[nf].y ? s[qg][nf][1] : MASKVAL);                  \
          p2 = __builtin_amdgcn_exp2f(MVR[nf].z ? s[qg][nf][2] : MASKVAL);                  \
          p3 = __builtin_amdgcn_exp2f(MVR[nf].w ? s[qg][nf][3] : MASKVAL);                  \
        }                                                                                   \
        wpk[nf][0] = __builtin_bit_cast(int, __builtin_amdgcn_cvt_pkrtz(p0, p1));           \
        wpk[nf][1] = __builtin_bit_cast(int, __builtin_amdgcn_cvt_pkrtz(p2, p3));           \
      }                                                                                     \
      _Pragma("unroll") for (int k2 = 0; k2 < 2; ++k2) {                                    \
        int A0 = wpk[2 * k2][0], B0 = wpk[2 * k2 + 1][0];                                   \
        int A1 = wpk[2 * k2][1], B1 = wpk[2 * k2 + 1][1];                                   \
        asm("v_permlane32_swap_b32 %0, %1" : "+v"(A0), "+v"(B0));                           \
        asm("v_permlane32_swap_b32 %0, %1" : "+v"(A1), "+v"(B1));                           \
        int SA0 = __builtin_amdgcn_ds_swizzle(A0, 0x401F);                                  \
        int SB0 = __builtin_amdgcn_ds_swizzle(B0, 0x401F);                                  \
        int SA1 = __builtin_amdgcn_ds_swizzle(A1, 0x401F);                                  \
        int SB1 = __builtin_amdgcn_ds_swizzle(B1, 0x401F);                                  \
        int c0 = oddhi ? SB0 : A0;                                                          \
        int c1 = oddhi ? SB1 : A1;                                                          \
        int c2 = oddhi ? B0 : SA0;                                                          \
        int c3 = oddhi ? B1 : SA1;                                                          \
        i32x4 cc = {c0, c1, c2, c3};                                                        \
        pf[qg][k2] = __builtin_bit_cast(f16x8, cc);                                         \
      }                                                                                     \
    }                                                                                       \
    __builtin_amdgcn_s_setprio(1);                                                          \
    _Pragma("unroll") for (int k2 = 0; k2 < 2; ++k2) {                                      \
      const char* vbase = (k2 ? kbase1 : kbase0) + (P) * 16384 + 8192;                      \
      _Pragma("unroll") for (int df = 0; df < 4; ++df) {                                    \
        f16x8 vf = *(const f16x8*)(vbase + df * 2048);                                      \
        oacc[0][df] = __builtin_amdgcn_mfma_f32_16x16x32_f16(pf[0][k2], vf, oacc[0][df], 0, 0, 0); \
        oacc[1][df] = __builtin_amdgcn_mfma_f32_16x16x32_f16(pf[1][k2], vf, oacc[1][df], 0, 0, 0); \
      }                                                                                     \
      lacc[0] = __builtin_amdgcn_mfma_f32_16x16x32_f16(pf[0][k2], ones, lacc[0], 0, 0, 0);  \
      lacc[1] = __builtin_amdgcn_mfma_f32_16x16x32_f16(pf[1][k2], ones, lacc[1], 0, 0, 0);  \
    }                                                                                       \
    __builtin_amdgcn_s_setprio(0);                                                          \
  } while (0)

  for (int kt = 0; kt < NT; kt += 2) {
    ATTN_ITER(kt, 0, mvA, mvB);
    ATTN_ITER(kt + 1, 1, mvB, mvA);
  }

  // epilogue: lacc[qg][r] is the row-sum for q = qg*16 + hi*4 + r (all lr equal)
#pragma unroll
  for (int qg = 0; qg < 2; ++qg) {
    f32x4 rinv;
#pragma unroll
    for (int r = 0; r < 4; ++r) rinv[r] = 1.0f / lacc[qg][r];
#pragma unroll
    for (int df = 0; df < 4; ++df)
#pragma unroll
      for (int r = 0; r < 4; ++r) {
        const int l = qr0 + qg * 16 + hi * 4 + r;
        Oa[(((size_t)b * L + l) * H + h) * HD + df * 16 + lr] = (f16)(oacc[qg][df][r] * rinv[r]);
      }
  }
}

// ---------------------------------------------------------------------------
extern "C" void kernel_launch(void* const* d_in, const int* in_sizes, int n_in,
                              void* d_out, int out_size, void* d_ws, size_t ws_size,
                              hipStream_t stream) {
  const float* x  = (const float*)d_in[0];
  const int* mask = (const int*)d_in[1];
  const float* Wq = (const float*)d_in[2];
  const float* bq = (const float*)d_in[3];
  const float* Wk = (const float*)d_in[4];
  const float* bk = (const float*)d_in[5];
  const float* Wv = (const float*)d_in[6];
  const float* bv = (const float*)d_in[7];
  const float* Wo = (const float*)d_in[8];
  const float* bo = (const float*)d_in[9];
  float* out = (float*)d_out;

  char* ws = (char*)d_ws;
  const size_t MB = 1u << 20;
  f16* xh  = (f16*)(ws);             // 4096x1024  (8 MB)
  f16* wqh = (f16*)(ws + 8 * MB);    // 1024x1024  (2 MB)
  f16* wkh = (f16*)(ws + 10 * MB);
  f16* wvh = (f16*)(ws + 12 * MB);
  f16* woh = (f16*)(ws + 14 * MB);
  f16* qh  = (f16*)(ws + 16 * MB);   // [2][16][2048][64], pre-scaled by ALPHA
  f16* kh  = (f16*)(ws + 24 * MB);   // [2][16][2048][64]
  f16* vth = (f16*)(ws + 32 * MB);   // [2][16][64][2048]
  f16* oah = (f16*)(ws + 40 * MB);   // [2][2048][16][64] = [4096][1024]

  conv_all<<<4096, 256, 0, stream>>>(x, Wq, Wk, Wv, Wo, xh, wqh, wkh, wvh, woh);

  gemm_qkv<<<dim3(8, 32, 3), 256, 0, stream>>>(xh, wqh, wkh, wvh, bq, bk, bv, qh, kh, vth);

  attn2w<<<dim3(1024), 128, 0, stream>>>(qh, kh, vth, mask, oah);

  gemm_o<<<dim3(8, 64), 256, 0, stream>>>(oah, woh, bo, out);
}

// Round 10
// 118.333 us; speedup vs baseline: 1.0115x; 1.0115x over previous
//
#include <hip/hip_runtime.h>
#include <hip/hip_bf16.h>

typedef _Float16 f16;
typedef _Float16 f16x8 __attribute__((ext_vector_type(8)));
typedef _Float16 f16x4 __attribute__((ext_vector_type(4)));
typedef float f32x4 __attribute__((ext_vector_type(4)));
typedef int i32x4 __attribute__((ext_vector_type(4)));

#define LDS_LOAD16(gptr, lptr)                                                             \
  __builtin_amdgcn_global_load_lds(                                                        \
      (const __attribute__((address_space(1))) unsigned int*)(gptr),                       \
      (__attribute__((address_space(3))) unsigned int*)(lptr), 16, 0, 0)

// 0.125 (1/sqrt(HD)) * log2(e): folded into Q so QK^T yields log2e-scaled scores
#define ALPHA 0.18033688f
// masked score: reference sets score=1e-9 (log2e domain)
#define MASKVAL 1.44269504e-9f

// ---------------------------------------------------------------------------
// fused fp32 -> fp16 conversion for x + 4 weight matrices
// ---------------------------------------------------------------------------
__global__ __launch_bounds__(256) void conv_all(const float* __restrict__ x,
                                                const float* __restrict__ Wq,
                                                const float* __restrict__ Wk,
                                                const float* __restrict__ Wv,
                                                const float* __restrict__ Wo,
                                                f16* __restrict__ xh, f16* __restrict__ wqh,
                                                f16* __restrict__ wkh, f16* __restrict__ wvh,
                                                f16* __restrict__ woh) {
  int i = blockIdx.x * 256 + threadIdx.x;
  const float* src;
  f16* dst;
  int off;
  if (i < 524288) {
    src = x; dst = xh; off = i;
  } else {
    int j = i - 524288;
    int w = j >> 17;
    off = j & 131071;
    src = (w == 0) ? Wq : (w == 1) ? Wk : (w == 2) ? Wv : Wo;
    dst = (w == 0) ? wqh : (w == 1) ? wkh : (w == 2) ? wvh : woh;
  }
  const float4* s4 = (const float4*)src;
  float4 a = s4[2 * off];
  float4 b = s4[2 * off + 1];
  f16x8 o = {(f16)a.x, (f16)a.y, (f16)a.z, (f16)a.w,
             (f16)b.x, (f16)b.y, (f16)b.z, (f16)b.w};
  *(f16x8*)(dst + (size_t)off * 8) = o;
}

// ---------------------------------------------------------------------------
// Fused QKV projection: z=0 -> Q (scaled by ALPHA), z=1 -> K, z=2 -> V^T.
// 2-phase pipeline, counted vmcnt(4), dbuf LDS (32 KB, 3 blocks/CU).
// ---------------------------------------------------------------------------
__global__ __launch_bounds__(256) void gemm_qkv(const f16* __restrict__ A,
                                                const f16* __restrict__ W0,
                                                const f16* __restrict__ W1,
                                                const f16* __restrict__ W2,
                                                const float* __restrict__ b0,
                                                const float* __restrict__ b1,
                                                const float* __restrict__ b2,
                                                f16* __restrict__ qo, f16* __restrict__ ko,
                                                f16* __restrict__ vo) {
  constexpr int K = 1024, BM = 128, BK = 32, NKT = K / BK;
  __shared__ f16 aT[2][BM * BK];
  __shared__ f16 bT[2][BM * BK];
  const int z = blockIdx.z;
  const f16* Bw = (z == 0) ? W0 : (z == 1) ? W1 : W2;
  const float* bias = (z == 0) ? b0 : (z == 1) ? b1 : b2;
  const int tid = threadIdx.x, wid = tid >> 6, lane = tid & 63;
  const int mb = blockIdx.y * BM, nb = blockIdx.x * BM;
  const int wr = wid >> 1, wc = wid & 1;
  const int lr = lane & 15, hi = lane >> 4;

  f32x4 acc[4][4] = {};

  const int r0 = tid >> 2, s0 = tid & 3;
  const int ci1 = 256 + tid, r1 = ci1 >> 2, s1 = ci1 & 3;

#define STAGE_QKV(bb, kt)                                                                   \
  do {                                                                                      \
    const int kb_ = (kt) * BK;                                                              \
    LDS_LOAD16(A + (size_t)(mb + r0) * K + kb_ + s0 * 8, (char*)aT[bb] + wid * 1024);       \
    LDS_LOAD16(Bw + (size_t)(nb + r0) * K + kb_ + s0 * 8, (char*)bT[bb] + wid * 1024);      \
    LDS_LOAD16(A + (size_t)(mb + r1) * K + kb_ + s1 * 8, (char*)aT[bb] + 4096 + wid * 1024);\
    LDS_LOAD16(Bw + (size_t)(nb + r1) * K + kb_ + s1 * 8, (char*)bT[bb] + 4096 + wid * 1024);\
  } while (0)

  STAGE_QKV(0, 0);
  for (int kt = 0; kt < NKT; ++kt) {
    const int p = kt & 1;
    if (kt + 1 < NKT) {
      STAGE_QKV(p ^ 1, kt + 1);
      asm volatile("s_waitcnt vmcnt(4)" ::: "memory");
    } else {
      asm volatile("s_waitcnt vmcnt(0)" ::: "memory");
    }
    __builtin_amdgcn_s_barrier();

    f16x8 af[4], bf[4];
#pragma unroll
    for (int i = 0; i < 4; ++i) af[i] = *(const f16x8*)&aT[p][(wr * 64 + i * 16 + lr) * BK + hi * 8];
#pragma unroll
    for (int j = 0; j < 4; ++j) bf[j] = *(const f16x8*)&bT[p][(wc * 64 + j * 16 + lr) * BK + hi * 8];
    __builtin_amdgcn_s_setprio(1);
#pragma unroll
    for (int i = 0; i < 4; ++i)
#pragma unroll
      for (int j = 0; j < 4; ++j)
        acc[i][j] = __builtin_amdgcn_mfma_f32_16x16x32_f16(af[i], bf[j], acc[i][j], 0, 0, 0);
    __builtin_amdgcn_s_setprio(0);
    __builtin_amdgcn_s_barrier();
  }

  const float scale = (z == 0) ? ALPHA : 1.0f;
#pragma unroll
  for (int i = 0; i < 4; ++i) {
#pragma unroll
    for (int j = 0; j < 4; ++j) {
      const int row = mb + wr * 64 + i * 16 + hi * 4;
      const int col = nb + wc * 64 + j * 16 + lr;
      const float bv = bias[col];
      const int hh = col >> 6, dd = col & 63;
      if (z == 2) {
        const int bb = row >> 11, l = row & 2047;
        f16x4 v4;
#pragma unroll
        for (int r = 0; r < 4; ++r) v4[r] = (f16)(acc[i][j][r] + bv);
        *(f16x4*)(vo + ((((size_t)bb * 16 + hh) * 64 + dd) * 2048 + l)) = v4;
      } else {
        f16* o = z ? ko : qo;
#pragma unroll
        for (int r = 0; r < 4; ++r) {
          const int m2 = row + r;
          const int bb = m2 >> 11, l = m2 & 2047;
          o[((((size_t)bb * 16 + hh) * 2048 + l) * 64) + dd] = (f16)((acc[i][j][r] + bv) * scale);
        }
      }
    }
  }
}

// ---------------------------------------------------------------------------
// Output projection: 64(M)x128(N) tile, 4 waves of 32x64, 2-phase pipeline.
// ---------------------------------------------------------------------------
__global__ __launch_bounds__(256) void gemm_o(const f16* __restrict__ A,
                                              const f16* __restrict__ W,
                                              const float* __restrict__ bias,
                                              float* __restrict__ out) {
  constexpr int K = 1024, N = 1024, BK = 32, NKT = K / BK;
  __shared__ f16 aT[2][64 * BK];
  __shared__ f16 bT[2][128 * BK];
  const int tid = threadIdx.x, wid = tid >> 6, lane = tid & 63;
  const int lr = lane & 15, hi = lane >> 4;
  const int mb = blockIdx.y * 64, nb = blockIdx.x * 128;
  const int wr = wid >> 1, wc = wid & 1;
  f32x4 acc[2][4] = {};
  const int ra = tid >> 2, sa = tid & 3;
  const int rb1 = (256 + tid) >> 2, sb1 = (256 + tid) & 3;

#define STAGE_O(bb, kt)                                                                     \
  do {                                                                                      \
    const int kb_ = (kt) * BK;                                                              \
    LDS_LOAD16(A + (size_t)(mb + ra) * K + kb_ + sa * 8, (char*)aT[bb] + wid * 1024);       \
    LDS_LOAD16(W + (size_t)(nb + ra) * K + kb_ + sa * 8, (char*)bT[bb] + wid * 1024);       \
    LDS_LOAD16(W + (size_t)(nb + rb1) * K + kb_ + sb1 * 8, (char*)bT[bb] + 4096 + wid * 1024);\
  } while (0)

  STAGE_O(0, 0);
  for (int kt = 0; kt < NKT; ++kt) {
    const int p = kt & 1;
    if (kt + 1 < NKT) {
      STAGE_O(p ^ 1, kt + 1);
      asm volatile("s_waitcnt vmcnt(3)" ::: "memory");
    } else {
      asm volatile("s_waitcnt vmcnt(0)" ::: "memory");
    }
    __builtin_amdgcn_s_barrier();
    f16x8 af[2], bf[4];
#pragma unroll
    for (int i = 0; i < 2; ++i) af[i] = *(const f16x8*)&aT[p][(wr * 32 + i * 16 + lr) * BK + hi * 8];
#pragma unroll
    for (int j = 0; j < 4; ++j) bf[j] = *(const f16x8*)&bT[p][(wc * 64 + j * 16 + lr) * BK + hi * 8];
    __builtin_amdgcn_s_setprio(1);
#pragma unroll
    for (int i = 0; i < 2; ++i)
#pragma unroll
      for (int j = 0; j < 4; ++j)
        acc[i][j] = __builtin_amdgcn_mfma_f32_16x16x32_f16(af[i], bf[j], acc[i][j], 0, 0, 0);
    __builtin_amdgcn_s_setprio(0);
    __builtin_amdgcn_s_barrier();
  }
#pragma unroll
  for (int i = 0; i < 2; ++i)
#pragma unroll
    for (int j = 0; j < 4; ++j) {
      const int col = nb + wc * 64 + j * 16 + lr;
      const float bv = bias[col];
#pragma unroll
      for (int r = 0; r < 4; ++r)
        out[(size_t)(mb + wr * 32 + i * 16 + hi * 4 + r) * N + col] = acc[i][j][r] + bv;
    }
}

// ---------------------------------------------------------------------------
// Flash attention v4: 4-wave blocks, 16 q/wave (64 q/block), KV tiles of 64.
// Doubles waves/SIMD (2->4) vs v3.1 for latency hiding; per-wave state and
// serial chain shrink.  K/V staging split 4 ways, dbuf, own-wave vmcnt(0) +
// one barrier/tile.  P in-register transpose (cvt_pkrtz + permlane32_swap +
// ds_swizzle(xor16) + cndmask).  Row-sums via ones-MFMA.  Mask all-ones
// fast path.  p = exp2(score*log2e); Q pre-scaled by ALPHA.
// ---------------------------------------------------------------------------
__global__ __launch_bounds__(256, 4) void attn4w(const f16* __restrict__ Qh,
                                                 const f16* __restrict__ Kh,
                                                 const f16* __restrict__ Vt,
                                                 const int* __restrict__ mask,
                                                 f16* __restrict__ Oa) {
  constexpr int L = 2048, HD = 64, H = 16, NT = L / 64;
  // [parity][ K(8KB) | V(8KB) ] = 32 KB total
  __shared__ __align__(16) char ldsb[32768];

  const int tid = threadIdx.x, w = tid >> 6, lane = tid & 63;
  const int lr = lane & 15, hi = lane >> 4;
  const int sw = lr & 7;
  const bool oddhi = (hi & 1) != 0;

  // XCD-bijective remap: bid bits [2:0]=xcd, [7:3]=qb, [9:8]=head-in-xcd
  const int bid = blockIdx.x;  // 1024 blocks
  const int head = (bid & 7) * 4 + (bid >> 8);
  const int qb = (bid >> 3) & 31;
  const int b = head >> 4, h = head & 15;
  const int qr0 = qb * 64 + w * 16;

  const f16* Qb = Qh + (size_t)head * L * HD;
  const f16* Kb = Kh + (size_t)head * L * HD;
  const f16* Vb = Vt + (size_t)head * HD * L;
  const int* mrow = mask + b * L;

  // whole-row mask scan (wave-uniform fast path; mask is 0/1 ints)
  int mred = 1;
  {
    const int4* m4 = (const int4*)mrow;
#pragma unroll
    for (int j = 0; j < 8; ++j) {
      int4 v = m4[lane + j * 64];
      mred &= v.x & v.y & v.z & v.w;
    }
  }
  const bool allm = __all(mred == 1);

  // staging: each wave stages rows [w*16, w*16+16) of K and of V^T (2 chunks each).
  const int srow = lane >> 3;
  const int schk = (lane & 7) ^ srow;

#define STAGE4W(bb, kt)                                                                     \
  _Pragma("unroll") for (int c = 0; c < 2; ++c) {                                           \
    LDS_LOAD16(Kb + (size_t)((kt) * 64 + w * 16 + c * 8 + srow) * HD + schk * 8,            \
               ldsb + (bb) * 16384 + w * 2048 + c * 1024);                                  \
    LDS_LOAD16(Vb + (size_t)(w * 16 + c * 8 + srow) * L + (kt) * 64 + schk * 8,             \
               ldsb + (bb) * 16384 + 8192 + w * 2048 + c * 1024);                           \
  }

  // per-lane LDS read bases (k2=0 / k2=1 chunk swizzle), all else via imms
  const char* kbase0 = ldsb + lr * 128 + ((hi ^ sw) * 16);
  const char* kbase1 = ldsb + lr * 128 + (((4 + hi) ^ sw) * 16);

  // Q fragments (B-operand), resident for the whole kernel
  f16x8 qf[2];
#pragma unroll
  for (int k2 = 0; k2 < 2; ++k2)
    qf[k2] = *(const f16x8*)&Qb[(size_t)(qr0 + lr) * HD + k2 * 32 + hi * 8];

  f32x4 oacc[4] = {};
  f32x4 lacc = {};
  const f32x4 zacc = {0.f, 0.f, 0.f, 0.f};
  const f16x8 ones = {1, 1, 1, 1, 1, 1, 1, 1};

  int4 mvA[4], mvB[4];
  if (!allm) {
#pragma unroll
    for (int nf = 0; nf < 4; ++nf) mvA[nf] = *(const int4*)&mrow[nf * 16 + hi * 4];
  }
  STAGE4W(0, 0);

#define ATTN_ITER(kt, P, MVR, MVL)                                                          \
  do {                                                                                      \
    asm volatile("s_waitcnt vmcnt(0)" ::: "memory");                                        \
    __builtin_amdgcn_s_barrier();                                                           \
    if ((kt) + 1 < NT) {                                                                    \
      if (!allm) {                                                                          \
        _Pragma("unroll") for (int nf = 0; nf < 4; ++nf)                                    \
            MVL[nf] = *(const int4*)&mrow[((kt) + 1) * 64 + nf * 16 + hi * 4];              \
      }                                                                                     \
      STAGE4W((P) ^ 1, (kt) + 1);                                                           \
    }                                                                                       \
    f16x8 kf[4][2];                                                                         \
    _Pragma("unroll") for (int nf = 0; nf < 4; ++nf) {                                      \
      kf[nf][0] = *(const f16x8*)(kbase0 + (P) * 16384 + nf * 2048);                        \
      kf[nf][1] = *(const f16x8*)(kbase1 + (P) * 16384 + nf * 2048);                        \
    }                                                                                       \
    f32x4 s[4];                                                                             \
    __builtin_amdgcn_s_setprio(1);                                                          \
    _Pragma("unroll") for (int nf = 0; nf < 4; ++nf) {                                      \
      f32x4 z = __builtin_amdgcn_mfma_f32_16x16x32_f16(kf[nf][0], qf[0], zacc, 0, 0, 0);    \
      s[nf] = __builtin_amdgcn_mfma_f32_16x16x32_f16(kf[nf][1], qf[1], z, 0, 0, 0);         \
    }                                                                                       \
    __builtin_amdgcn_s_setprio(0);                                                          \
    int wpk[4][2];                                                                          \
    _Pragma("unroll") for (int nf = 0; nf < 4; ++nf) {                                      \
      float p0, p1, p2, p3;                                                                 \
      if (allm) {                                                                           \
        p0 = __builtin_amdgcn_exp2f(s[nf][0]);                                              \
        p1 = __builtin_amdgcn_exp2f(s[nf][1]);                                              \
        p2 = __builtin_amdgcn_exp2f(s[nf][2]);                                              \
        p3 = __builtin_amdgcn_exp2f(s[nf][3]);                                              \
      } else {                                                                              \
        p0 = __builtin_amdgcn_exp2f(MVR[nf].x ? s[nf][0] : MASKVAL);                        \
        p1 = __builtin_amdgcn_exp2f(MVR[nf].y ? s[nf][1] : MASKVAL);                        \
        p2 = __builtin_amdgcn_exp2f(MVR[nf].z ? s[nf][2] : MASKVAL);                        \
        p3 = __builtin_amdgcn_exp2f(MVR[nf].w ? s[nf][3] : MASKVAL);                        \
      }                                                                                     \
      wpk[nf][0] = __builtin_bit_cast(int, __builtin_amdgcn_cvt_pkrtz(p0, p1));             \
      wpk[nf][1] = __builtin_bit_cast(int, __builtin_amdgcn_cvt_pkrtz(p2, p3));             \
    }                                                                                       \
    f16x8 pf[2];                                                                            \
    _Pragma("unroll") for (int k2 = 0; k2 < 2; ++k2) {                                      \
      int A0 = wpk[2 * k2][0], B0 = wpk[2 * k2 + 1][0];                                     \
      int A1 = wpk[2 * k2][1], B1 = wpk[2 * k2 + 1][1];                                     \
      asm("v_permlane32_swap_b32 %0, %1" : "+v"(A0), "+v"(B0));                             \
      asm("v_permlane32_swap_b32 %0, %1" : "+v"(A1), "+v"(B1));                             \
      int SA0 = __builtin_amdgcn_ds_swizzle(A0, 0x401F);                                    \
      int SB0 = __builtin_amdgcn_ds_swizzle(B0, 0x401F);                                    \
      int SA1 = __builtin_amdgcn_ds_swizzle(A1, 0x401F);                                    \
      int SB1 = __builtin_amdgcn_ds_swizzle(B1, 0x401F);                                    \
      int c0 = oddhi ? SB0 : A0;                                                            \
      int c1 = oddhi ? SB1 : A1;                                                            \
      int c2 = oddhi ? B0 : SA0;                                                            \
      int c3 = oddhi ? B1 : SA1;                                                            \
      i32x4 cc = {c0, c1, c2, c3};                                                          \
      pf[k2] = __builtin_bit_cast(f16x8, cc);                                               \
    }                                                                                       \
    __builtin_amdgcn_s_setprio(1);                                                          \
    _Pragma("unroll") for (int k2 = 0; k2 < 2; ++k2) {                                      \
      const char* vbase = (k2 ? kbase1 : kbase0) + (P) * 16384 + 8192;                      \
      _Pragma("unroll") for (int df = 0; df < 4; ++df) {                                    \
        f16x8 vf = *(const f16x8*)(vbase + df * 2048);                                      \
        oacc[df] = __builtin_amdgcn_mfma_f32_16x16x32_f16(pf[k2], vf, oacc[df], 0, 0, 0);   \
      }                                                                                     \
      lacc = __builtin_amdgcn_mfma_f32_16x16x32_f16(pf[k2], ones, lacc, 0, 0, 0);           \
    }                                                                                       \
    __builtin_amdgcn_s_setprio(0);                                                          \
  } while (0)

  for (int kt = 0; kt < NT; kt += 2) {
    ATTN_ITER(kt, 0, mvA, mvB);
    ATTN_ITER(kt + 1, 1, mvB, mvA);
  }

  // epilogue: lacc[r] is the row-sum for q = hi*4 + r (all lr identical)
  f32x4 rinv;
#pragma unroll
  for (int r = 0; r < 4; ++r) rinv[r] = 1.0f / lacc[r];
#pragma unroll
  for (int df = 0; df < 4; ++df)
#pragma unroll
    for (int r = 0; r < 4; ++r) {
      const int l = qr0 + hi * 4 + r;
      Oa[(((size_t)b * L + l) * H + h) * HD + df * 16 + lr] = (f16)(oacc[df][r] * rinv[r]);
    }
}

// ---------------------------------------------------------------------------
extern "C" void kernel_launch(void* const* d_in, const int* in_sizes, int n_in,
                              void* d_out, int out_size, void* d_ws, size_t ws_size,
                              hipStream_t stream) {
  const float* x  = (const float*)d_in[0];
  const int* mask = (const int*)d_in[1];
  const float* Wq = (const float*)d_in[2];
  const float* bq = (const float*)d_in[3];
  const float* Wk = (const float*)d_in[4];
  const float* bk = (const float*)d_in[5];
  const float* Wv = (const float*)d_in[6];
  const float* bv = (const float*)d_in[7];
  const float* Wo = (const float*)d_in[8];
  const float* bo = (const float*)d_in[9];
  float* out = (float*)d_out;

  char* ws = (char*)d_ws;
  const size_t MB = 1u << 20;
  f16* xh  = (f16*)(ws);             // 4096x1024  (8 MB)
  f16* wqh = (f16*)(ws + 8 * MB);    // 1024x1024  (2 MB)
  f16* wkh = (f16*)(ws + 10 * MB);
  f16* wvh = (f16*)(ws + 12 * MB);
  f16* woh = (f16*)(ws + 14 * MB);
  f16* qh  = (f16*)(ws + 16 * MB);   // [2][16][2048][64], pre-scaled by ALPHA
  f16* kh  = (f16*)(ws + 24 * MB);   // [2][16][2048][64]
  f16* vth = (f16*)(ws + 32 * MB);   // [2][16][64][2048]
  f16* oah = (f16*)(ws + 40 * MB);   // [2][2048][16][64] = [4096][1024]

  conv_all<<<4096, 256, 0, stream>>>(x, Wq, Wk, Wv, Wo, xh, wqh, wkh, wvh, woh);

  gemm_qkv<<<dim3(8, 32, 3), 256, 0, stream>>>(xh, wqh, wkh, wvh, bq, bk, bv, qh, kh, vth);

  attn4w<<<dim3(1024), 256, 0, stream>>>(qh, kh, vth, mask, oah);

  gemm_o<<<dim3(8, 64), 256, 0, stream>>>(oah, woh, bo, out);
}

// Round 11
// 117.302 us; speedup vs baseline: 1.0204x; 1.0088x over previous
//
#include <hip/hip_runtime.h>
#include <hip/hip_bf16.h>

typedef _Float16 f16;
typedef _Float16 f16x8 __attribute__((ext_vector_type(8)));
typedef _Float16 f16x4 __attribute__((ext_vector_type(4)));
typedef float f32x4 __attribute__((ext_vector_type(4)));
typedef int i32x4 __attribute__((ext_vector_type(4)));

#define LDS_LOAD16(gptr, lptr)                                                             \
  __builtin_amdgcn_global_load_lds(                                                        \
      (const __attribute__((address_space(1))) unsigned int*)(gptr),                       \
      (__attribute__((address_space(3))) unsigned int*)(lptr), 16, 0, 0)

// 0.125 (1/sqrt(HD)) * log2(e): folded into Q so QK^T yields log2e-scaled scores
#define ALPHA 0.18033688f
// masked score: reference sets score=1e-9 (log2e domain)
#define MASKVAL 1.44269504e-9f

// ---------------------------------------------------------------------------
// fused fp32 -> fp16 conversion for x + 4 weight matrices
// ---------------------------------------------------------------------------
__global__ __launch_bounds__(256) void conv_all(const float* __restrict__ x,
                                                const float* __restrict__ Wq,
                                                const float* __restrict__ Wk,
                                                const float* __restrict__ Wv,
                                                const float* __restrict__ Wo,
                                                f16* __restrict__ xh, f16* __restrict__ wqh,
                                                f16* __restrict__ wkh, f16* __restrict__ wvh,
                                                f16* __restrict__ woh) {
  int i = blockIdx.x * 256 + threadIdx.x;
  const float* src;
  f16* dst;
  int off;
  if (i < 524288) {
    src = x; dst = xh; off = i;
  } else {
    int j = i - 524288;
    int w = j >> 17;
    off = j & 131071;
    src = (w == 0) ? Wq : (w == 1) ? Wk : (w == 2) ? Wv : Wo;
    dst = (w == 0) ? wqh : (w == 1) ? wkh : (w == 2) ? wvh : woh;
  }
  const float4* s4 = (const float4*)src;
  float4 a = s4[2 * off];
  float4 b = s4[2 * off + 1];
  f16x8 o = {(f16)a.x, (f16)a.y, (f16)a.z, (f16)a.w,
             (f16)b.x, (f16)b.y, (f16)b.z, (f16)b.w};
  *(f16x8*)(dst + (size_t)off * 8) = o;
}

// ---------------------------------------------------------------------------
// Fused QKV projection: z=0 -> Q (scaled by ALPHA), z=1 -> K, z=2 -> V^T.
// 2-phase pipeline, counted vmcnt(4), dbuf LDS.  1D grid 768 with
// XCD-chunked bijective swizzle: XCD x gets rids [x*96, x*96+95] so its
// L2 holds one z's W (2MB) + a contiguous run of A panels.
// ---------------------------------------------------------------------------
__global__ __launch_bounds__(256) void gemm_qkv(const f16* __restrict__ A,
                                                const f16* __restrict__ W0,
                                                const f16* __restrict__ W1,
                                                const f16* __restrict__ W2,
                                                const float* __restrict__ b0,
                                                const float* __restrict__ b1,
                                                const float* __restrict__ b2,
                                                f16* __restrict__ qo, f16* __restrict__ ko,
                                                f16* __restrict__ vo) {
  constexpr int K = 1024, BM = 128, BK = 32, NKT = K / BK;
  __shared__ f16 aT[2][BM * BK];
  __shared__ f16 bT[2][BM * BK];
  const int rid = (blockIdx.x & 7) * 96 + (blockIdx.x >> 3);
  const int z = rid >> 8;
  const f16* Bw = (z == 0) ? W0 : (z == 1) ? W1 : W2;
  const float* bias = (z == 0) ? b0 : (z == 1) ? b1 : b2;
  const int tid = threadIdx.x, wid = tid >> 6, lane = tid & 63;
  const int mb = ((rid >> 3) & 31) * BM, nb = (rid & 7) * BM;
  const int wr = wid >> 1, wc = wid & 1;
  const int lr = lane & 15, hi = lane >> 4;

  f32x4 acc[4][4] = {};

  const int r0 = tid >> 2, s0 = tid & 3;
  const int ci1 = 256 + tid, r1 = ci1 >> 2, s1 = ci1 & 3;

#define STAGE_QKV(bb, kt)                                                                   \
  do {                                                                                      \
    const int kb_ = (kt) * BK;                                                              \
    LDS_LOAD16(A + (size_t)(mb + r0) * K + kb_ + s0 * 8, (char*)aT[bb] + wid * 1024);       \
    LDS_LOAD16(Bw + (size_t)(nb + r0) * K + kb_ + s0 * 8, (char*)bT[bb] + wid * 1024);      \
    LDS_LOAD16(A + (size_t)(mb + r1) * K + kb_ + s1 * 8, (char*)aT[bb] + 4096 + wid * 1024);\
    LDS_LOAD16(Bw + (size_t)(nb + r1) * K + kb_ + s1 * 8, (char*)bT[bb] + 4096 + wid * 1024);\
  } while (0)

  STAGE_QKV(0, 0);
  for (int kt = 0; kt < NKT; ++kt) {
    const int p = kt & 1;
    if (kt + 1 < NKT) {
      STAGE_QKV(p ^ 1, kt + 1);
      asm volatile("s_waitcnt vmcnt(4)" ::: "memory");
    } else {
      asm volatile("s_waitcnt vmcnt(0)" ::: "memory");
    }
    __builtin_amdgcn_s_barrier();

    f16x8 af[4], bf[4];
#pragma unroll
    for (int i = 0; i < 4; ++i) af[i] = *(const f16x8*)&aT[p][(wr * 64 + i * 16 + lr) * BK + hi * 8];
#pragma unroll
    for (int j = 0; j < 4; ++j) bf[j] = *(const f16x8*)&bT[p][(wc * 64 + j * 16 + lr) * BK + hi * 8];
    __builtin_amdgcn_s_setprio(1);
#pragma unroll
    for (int i = 0; i < 4; ++i)
#pragma unroll
      for (int j = 0; j < 4; ++j)
        acc[i][j] = __builtin_amdgcn_mfma_f32_16x16x32_f16(af[i], bf[j], acc[i][j], 0, 0, 0);
    __builtin_amdgcn_s_setprio(0);
    __builtin_amdgcn_s_barrier();
  }

  const float scale = (z == 0) ? ALPHA : 1.0f;
#pragma unroll
  for (int i = 0; i < 4; ++i) {
#pragma unroll
    for (int j = 0; j < 4; ++j) {
      const int row = mb + wr * 64 + i * 16 + hi * 4;
      const int col = nb + wc * 64 + j * 16 + lr;
      const float bv = bias[col];
      const int hh = col >> 6, dd = col & 63;
      if (z == 2) {
        const int bb = row >> 11, l = row & 2047;
        f16x4 v4;
#pragma unroll
        for (int r = 0; r < 4; ++r) v4[r] = (f16)(acc[i][j][r] + bv);
        *(f16x4*)(vo + ((((size_t)bb * 16 + hh) * 64 + dd) * 2048 + l)) = v4;
      } else {
        f16* o = z ? ko : qo;
#pragma unroll
        for (int r = 0; r < 4; ++r) {
          const int m2 = row + r;
          const int bb = m2 >> 11, l = m2 & 2047;
          o[((((size_t)bb * 16 + hh) * 2048 + l) * 64) + dd] = (f16)((acc[i][j][r] + bv) * scale);
        }
      }
    }
  }
}

// ---------------------------------------------------------------------------
// Output projection: 64(M)x128(N) tile, 2-phase pipeline, XCD-chunked
// swizzle (512 = 8 x 64 contiguous rids per XCD).
// ---------------------------------------------------------------------------
__global__ __launch_bounds__(256) void gemm_o(const f16* __restrict__ A,
                                              const f16* __restrict__ W,
                                              const float* __restrict__ bias,
                                              float* __restrict__ out) {
  constexpr int K = 1024, N = 1024, BK = 32, NKT = K / BK;
  __shared__ f16 aT[2][64 * BK];
  __shared__ f16 bT[2][128 * BK];
  const int rid = (blockIdx.x & 7) * 64 + (blockIdx.x >> 3);
  const int tid = threadIdx.x, wid = tid >> 6, lane = tid & 63;
  const int lr = lane & 15, hi = lane >> 4;
  const int mb = (rid >> 3) * 64, nb = (rid & 7) * 128;
  const int wr = wid >> 1, wc = wid & 1;
  f32x4 acc[2][4] = {};
  const int ra = tid >> 2, sa = tid & 3;
  const int rb1 = (256 + tid) >> 2, sb1 = (256 + tid) & 3;

#define STAGE_O(bb, kt)                                                                     \
  do {                                                                                      \
    const int kb_ = (kt) * BK;                                                              \
    LDS_LOAD16(A + (size_t)(mb + ra) * K + kb_ + sa * 8, (char*)aT[bb] + wid * 1024);       \
    LDS_LOAD16(W + (size_t)(nb + ra) * K + kb_ + sa * 8, (char*)bT[bb] + wid * 1024);       \
    LDS_LOAD16(W + (size_t)(nb + rb1) * K + kb_ + sb1 * 8, (char*)bT[bb] + 4096 + wid * 1024);\
  } while (0)

  STAGE_O(0, 0);
  for (int kt = 0; kt < NKT; ++kt) {
    const int p = kt & 1;
    if (kt + 1 < NKT) {
      STAGE_O(p ^ 1, kt + 1);
      asm volatile("s_waitcnt vmcnt(3)" ::: "memory");
    } else {
      asm volatile("s_waitcnt vmcnt(0)" ::: "memory");
    }
    __builtin_amdgcn_s_barrier();
    f16x8 af[2], bf[4];
#pragma unroll
    for (int i = 0; i < 2; ++i) af[i] = *(const f16x8*)&aT[p][(wr * 32 + i * 16 + lr) * BK + hi * 8];
#pragma unroll
    for (int j = 0; j < 4; ++j) bf[j] = *(const f16x8*)&bT[p][(wc * 64 + j * 16 + lr) * BK + hi * 8];
    __builtin_amdgcn_s_setprio(1);
#pragma unroll
    for (int i = 0; i < 2; ++i)
#pragma unroll
      for (int j = 0; j < 4; ++j)
        acc[i][j] = __builtin_amdgcn_mfma_f32_16x16x32_f16(af[i], bf[j], acc[i][j], 0, 0, 0);
    __builtin_amdgcn_s_setprio(0);
    __builtin_amdgcn_s_barrier();
  }
#pragma unroll
  for (int i = 0; i < 2; ++i)
#pragma unroll
    for (int j = 0; j < 4; ++j) {
      const int col = nb + wc * 64 + j * 16 + lr;
      const float bv = bias[col];
#pragma unroll
      for (int r = 0; r < 4; ++r)
        out[(size_t)(mb + wr * 32 + i * 16 + hi * 4 + r) * N + col] = acc[i][j][r] + bv;
    }
}

// ---------------------------------------------------------------------------
// Flash attention v5: 4-wave blocks, 16 q/wave, KV tiles of 64, dbuf staging,
// one barrier/tile.  P transpose fully in VALU: word0,word2 =
// permlane16_swap(permlane32_swap(A,B)) -- zero DS ops (was 8 ds_swizzle +
// 8 cndmask/tile).  Row-sums via ones-MFMA; mask all-ones fast path;
// p = exp2(score*log2e); Q pre-scaled by ALPHA.
// ---------------------------------------------------------------------------
__global__ __launch_bounds__(256, 4) void attn4w(const f16* __restrict__ Qh,
                                                 const f16* __restrict__ Kh,
                                                 const f16* __restrict__ Vt,
                                                 const int* __restrict__ mask,
                                                 f16* __restrict__ Oa) {
  constexpr int L = 2048, HD = 64, H = 16, NT = L / 64;
  // [parity][ K(8KB) | V(8KB) ] = 32 KB total
  __shared__ __align__(16) char ldsb[32768];

  const int tid = threadIdx.x, w = tid >> 6, lane = tid & 63;
  const int lr = lane & 15, hi = lane >> 4;
  const int sw = lr & 7;

  // XCD-bijective remap: bid bits [2:0]=xcd, [7:3]=qb, [9:8]=head-in-xcd
  const int bid = blockIdx.x;  // 1024 blocks
  const int head = (bid & 7) * 4 + (bid >> 8);
  const int qb = (bid >> 3) & 31;
  const int b = head >> 4, h = head & 15;
  const int qr0 = qb * 64 + w * 16;

  const f16* Qb = Qh + (size_t)head * L * HD;
  const f16* Kb = Kh + (size_t)head * L * HD;
  const f16* Vb = Vt + (size_t)head * HD * L;
  const int* mrow = mask + b * L;

  // whole-row mask scan (wave-uniform fast path; mask is 0/1 ints)
  int mred = 1;
  {
    const int4* m4 = (const int4*)mrow;
#pragma unroll
    for (int j = 0; j < 8; ++j) {
      int4 v = m4[lane + j * 64];
      mred &= v.x & v.y & v.z & v.w;
    }
  }
  const bool allm = __all(mred == 1);

  // staging: each wave stages rows [w*16, w*16+16) of K and of V^T (2 chunks each).
  const int srow = lane >> 3;
  const int schk = (lane & 7) ^ srow;

#define STAGE4W(bb, kt)                                                                     \
  _Pragma("unroll") for (int c = 0; c < 2; ++c) {                                           \
    LDS_LOAD16(Kb + (size_t)((kt) * 64 + w * 16 + c * 8 + srow) * HD + schk * 8,            \
               ldsb + (bb) * 16384 + w * 2048 + c * 1024);                                  \
    LDS_LOAD16(Vb + (size_t)(w * 16 + c * 8 + srow) * L + (kt) * 64 + schk * 8,             \
               ldsb + (bb) * 16384 + 8192 + w * 2048 + c * 1024);                           \
  }

  // per-lane LDS read bases (k2=0 / k2=1 chunk swizzle), all else via imms
  const char* kbase0 = ldsb + lr * 128 + ((hi ^ sw) * 16);
  const char* kbase1 = ldsb + lr * 128 + (((4 + hi) ^ sw) * 16);

  // Q fragments (B-operand), resident for the whole kernel
  f16x8 qf[2];
#pragma unroll
  for (int k2 = 0; k2 < 2; ++k2)
    qf[k2] = *(const f16x8*)&Qb[(size_t)(qr0 + lr) * HD + k2 * 32 + hi * 8];

  f32x4 oacc[4] = {};
  f32x4 lacc = {};
  const f32x4 zacc = {0.f, 0.f, 0.f, 0.f};
  const f16x8 ones = {1, 1, 1, 1, 1, 1, 1, 1};

  int4 mvA[4], mvB[4];
  if (!allm) {
#pragma unroll
    for (int nf = 0; nf < 4; ++nf) mvA[nf] = *(const int4*)&mrow[nf * 16 + hi * 4];
  }
  STAGE4W(0, 0);

#define ATTN_ITER(kt, P, MVR, MVL)                                                          \
  do {                                                                                      \
    asm volatile("s_waitcnt vmcnt(0)" ::: "memory");                                        \
    __builtin_amdgcn_s_barrier();                                                           \
    if ((kt) + 1 < NT) {                                                                    \
      if (!allm) {                                                                          \
        _Pragma("unroll") for (int nf = 0; nf < 4; ++nf)                                    \
            MVL[nf] = *(const int4*)&mrow[((kt) + 1) * 64 + nf * 16 + hi * 4];              \
      }                                                                                     \
      STAGE4W((P) ^ 1, (kt) + 1);                                                           \
    }                                                                                       \
    f16x8 kf[4][2];                                                                         \
    _Pragma("unroll") for (int nf = 0; nf < 4; ++nf) {                                      \
      kf[nf][0] = *(const f16x8*)(kbase0 + (P) * 16384 + nf * 2048);                        \
      kf[nf][1] = *(const f16x8*)(kbase1 + (P) * 16384 + nf * 2048);                        \
    }                                                                                       \
    f32x4 s[4];                                                                             \
    __builtin_amdgcn_s_setprio(1);                                                          \
    _Pragma("unroll") for (int nf = 0; nf < 4; ++nf) {                                      \
      f32x4 z = __builtin_amdgcn_mfma_f32_16x16x32_f16(kf[nf][0], qf[0], zacc, 0, 0, 0);    \
      s[nf] = __builtin_amdgcn_mfma_f32_16x16x32_f16(kf[nf][1], qf[1], z, 0, 0, 0);         \
    }                                                                                       \
    __builtin_amdgcn_s_setprio(0);                                                          \
    int wpk[4][2];                                                                          \
    _Pragma("unroll") for (int nf = 0; nf < 4; ++nf) {                                      \
      float p0, p1, p2, p3;                                                                 \
      if (allm) {                                                                           \
        p0 = __builtin_amdgcn_exp2f(s[nf][0]);                                              \
        p1 = __builtin_amdgcn_exp2f(s[nf][1]);                                              \
        p2 = __builtin_amdgcn_exp2f(s[nf][2]);                                              \
        p3 = __builtin_amdgcn_exp2f(s[nf][3]);                                              \
      } else {                                                                              \
        p0 = __builtin_amdgcn_exp2f(MVR[nf].x ? s[nf][0] : MASKVAL);                        \
        p1 = __builtin_amdgcn_exp2f(MVR[nf].y ? s[nf][1] : MASKVAL);                        \
        p2 = __builtin_amdgcn_exp2f(MVR[nf].z ? s[nf][2] : MASKVAL);                        \
        p3 = __builtin_amdgcn_exp2f(MVR[nf].w ? s[nf][3] : MASKVAL);                        \
      }                                                                                     \
      wpk[nf][0] = __builtin_bit_cast(int, __builtin_amdgcn_cvt_pkrtz(p0, p1));             \
      wpk[nf][1] = __builtin_bit_cast(int, __builtin_amdgcn_cvt_pkrtz(p2, p3));             \
    }                                                                                       \
    f16x8 pf[2];                                                                            \
    _Pragma("unroll") for (int k2 = 0; k2 < 2; ++k2) {                                      \
      int A0 = wpk[2 * k2][0], B0 = wpk[2 * k2 + 1][0];                                     \
      int A1 = wpk[2 * k2][1], B1 = wpk[2 * k2 + 1][1];                                     \
      asm("v_permlane32_swap_b32 %0, %1" : "+v"(A0), "+v"(B0));                             \
      asm("v_permlane16_swap_b32 %0, %1" : "+v"(A0), "+v"(B0));                             \
      asm("v_permlane32_swap_b32 %0, %1" : "+v"(A1), "+v"(B1));                             \
      asm("v_permlane16_swap_b32 %0, %1" : "+v"(A1), "+v"(B1));                             \
      i32x4 cc = {A0, A1, B0, B1};                                                          \
      pf[k2] = __builtin_bit_cast(f16x8, cc);                                               \
    }                                                                                       \
    __builtin_amdgcn_s_setprio(1);                                                          \
    _Pragma("unroll") for (int k2 = 0; k2 < 2; ++k2) {                                      \
      const char* vbase = (k2 ? kbase1 : kbase0) + (P) * 16384 + 8192;                      \
      _Pragma("unroll") for (int df = 0; df < 4; ++df) {                                    \
        f16x8 vf = *(const f16x8*)(vbase + df * 2048);                                      \
        oacc[df] = __builtin_amdgcn_mfma_f32_16x16x32_f16(pf[k2], vf, oacc[df], 0, 0, 0);   \
      }                                                                                     \
      lacc = __builtin_amdgcn_mfma_f32_16x16x32_f16(pf[k2], ones, lacc, 0, 0, 0);           \
    }                                                                                       \
    __builtin_amdgcn_s_setprio(0);                                                          \
  } while (0)

  for (int kt = 0; kt < NT; kt += 2) {
    ATTN_ITER(kt, 0, mvA, mvB);
    ATTN_ITER(kt + 1, 1, mvB, mvA);
  }

  // epilogue: lacc[r] is the row-sum for q = hi*4 + r (all lr identical)
  f32x4 rinv;
#pragma unroll
  for (int r = 0; r < 4; ++r) rinv[r] = 1.0f / lacc[r];
#pragma unroll
  for (int df = 0; df < 4; ++df)
#pragma unroll
    for (int r = 0; r < 4; ++r) {
      const int l = qr0 + hi * 4 + r;
      Oa[(((size_t)b * L + l) * H + h) * HD + df * 16 + lr] = (f16)(oacc[df][r] * rinv[r]);
    }
}

// ---------------------------------------------------------------------------
extern "C" void kernel_launch(void* const* d_in, const int* in_sizes, int n_in,
                              void* d_out, int out_size, void* d_ws, size_t ws_size,
                              hipStream_t stream) {
  const float* x  = (const float*)d_in[0];
  const int* mask = (const int*)d_in[1];
  const float* Wq = (const float*)d_in[2];
  const float* bq = (const float*)d_in[3];
  const float* Wk = (const float*)d_in[4];
  const float* bk = (const float*)d_in[5];
  const float* Wv = (const float*)d_in[6];
  const float* bv = (const float*)d_in[7];
  const float* Wo = (const float*)d_in[8];
  const float* bo = (const float*)d_in[9];
  float* out = (float*)d_out;

  char* ws = (char*)d_ws;
  const size_t MB = 1u << 20;
  f16* xh  = (f16*)(ws);             // 4096x1024  (8 MB)
  f16* wqh = (f16*)(ws + 8 * MB);    // 1024x1024  (2 MB)
  f16* wkh = (f16*)(ws + 10 * MB);
  f16* wvh = (f16*)(ws + 12 * MB);
  f16* woh = (f16*)(ws + 14 * MB);
  f16* qh  = (f16*)(ws + 16 * MB);   // [2][16][2048][64], pre-scaled by ALPHA
  f16* kh  = (f16*)(ws + 24 * MB);   // [2][16][2048][64]
  f16* vth = (f16*)(ws + 32 * MB);   // [2][16][64][2048]
  f16* oah = (f16*)(ws + 40 * MB);   // [2][2048][16][64] = [4096][1024]

  conv_all<<<4096, 256, 0, stream>>>(x, Wq, Wk, Wv, Wo, xh, wqh, wkh, wvh, woh);

  gemm_qkv<<<768, 256, 0, stream>>>(xh, wqh, wkh, wvh, bq, bk, bv, qh, kh, vth);

  attn4w<<<dim3(1024), 256, 0, stream>>>(qh, kh, vth, mask, oah);

  gemm_o<<<512, 256, 0, stream>>>(oah, woh, bo, out);
}

// Round 12
// 117.160 us; speedup vs baseline: 1.0217x; 1.0012x over previous
//
#include <hip/hip_runtime.h>
#include <hip/hip_bf16.h>

typedef _Float16 f16;
typedef _Float16 f16x8 __attribute__((ext_vector_type(8)));
typedef _Float16 f16x4 __attribute__((ext_vector_type(4)));
typedef float f32x4 __attribute__((ext_vector_type(4)));
typedef float f32x16 __attribute__((ext_vector_type(16)));
typedef int i32x4 __attribute__((ext_vector_type(4)));

#define LDS_LOAD16(gptr, lptr)                                                             \
  __builtin_amdgcn_global_load_lds(                                                        \
      (const __attribute__((address_space(1))) unsigned int*)(gptr),                       \
      (__attribute__((address_space(3))) unsigned int*)(lptr), 16, 0, 0)

// 0.125 (1/sqrt(HD)) * log2(e): folded into Q so QK^T yields log2e-scaled scores
#define ALPHA 0.18033688f
// masked score: reference sets score=1e-9 (log2e domain)
#define MASKVAL 1.44269504e-9f

// ---------------------------------------------------------------------------
// fused fp32 -> fp16 conversion for x + 4 weight matrices
// ---------------------------------------------------------------------------
__global__ __launch_bounds__(256) void conv_all(const float* __restrict__ x,
                                                const float* __restrict__ Wq,
                                                const float* __restrict__ Wk,
                                                const float* __restrict__ Wv,
                                                const float* __restrict__ Wo,
                                                f16* __restrict__ xh, f16* __restrict__ wqh,
                                                f16* __restrict__ wkh, f16* __restrict__ wvh,
                                                f16* __restrict__ woh) {
  int i = blockIdx.x * 256 + threadIdx.x;
  const float* src;
  f16* dst;
  int off;
  if (i < 524288) {
    src = x; dst = xh; off = i;
  } else {
    int j = i - 524288;
    int w = j >> 17;
    off = j & 131071;
    src = (w == 0) ? Wq : (w == 1) ? Wk : (w == 2) ? Wv : Wo;
    dst = (w == 0) ? wqh : (w == 1) ? wkh : (w == 2) ? wvh : woh;
  }
  const float4* s4 = (const float4*)src;
  float4 a = s4[2 * off];
  float4 b = s4[2 * off + 1];
  f16x8 o = {(f16)a.x, (f16)a.y, (f16)a.z, (f16)a.w,
             (f16)b.x, (f16)b.y, (f16)b.z, (f16)b.w};
  *(f16x8*)(dst + (size_t)off * 8) = o;
}

// ---------------------------------------------------------------------------
// Fused QKV projection: z=0 -> Q (scaled by ALPHA), z=1 -> K, z=2 -> V^T.
// 2-phase pipeline, counted vmcnt(4), dbuf LDS, XCD-chunked swizzle.
// ---------------------------------------------------------------------------
__global__ __launch_bounds__(256) void gemm_qkv(const f16* __restrict__ A,
                                                const f16* __restrict__ W0,
                                                const f16* __restrict__ W1,
                                                const f16* __restrict__ W2,
                                                const float* __restrict__ b0,
                                                const float* __restrict__ b1,
                                                const float* __restrict__ b2,
                                                f16* __restrict__ qo, f16* __restrict__ ko,
                                                f16* __restrict__ vo) {
  constexpr int K = 1024, BM = 128, BK = 32, NKT = K / BK;
  __shared__ f16 aT[2][BM * BK];
  __shared__ f16 bT[2][BM * BK];
  const int rid = (blockIdx.x & 7) * 96 + (blockIdx.x >> 3);
  const int z = rid >> 8;
  const f16* Bw = (z == 0) ? W0 : (z == 1) ? W1 : W2;
  const float* bias = (z == 0) ? b0 : (z == 1) ? b1 : b2;
  const int tid = threadIdx.x, wid = tid >> 6, lane = tid & 63;
  const int mb = ((rid >> 3) & 31) * BM, nb = (rid & 7) * BM;
  const int wr = wid >> 1, wc = wid & 1;
  const int lr = lane & 15, hi = lane >> 4;

  f32x4 acc[4][4] = {};

  const int r0 = tid >> 2, s0 = tid & 3;
  const int ci1 = 256 + tid, r1 = ci1 >> 2, s1 = ci1 & 3;

#define STAGE_QKV(bb, kt)                                                                   \
  do {                                                                                      \
    const int kb_ = (kt) * BK;                                                              \
    LDS_LOAD16(A + (size_t)(mb + r0) * K + kb_ + s0 * 8, (char*)aT[bb] + wid * 1024);       \
    LDS_LOAD16(Bw + (size_t)(nb + r0) * K + kb_ + s0 * 8, (char*)bT[bb] + wid * 1024);      \
    LDS_LOAD16(A + (size_t)(mb + r1) * K + kb_ + s1 * 8, (char*)aT[bb] + 4096 + wid * 1024);\
    LDS_LOAD16(Bw + (size_t)(nb + r1) * K + kb_ + s1 * 8, (char*)bT[bb] + 4096 + wid * 1024);\
  } while (0)

  STAGE_QKV(0, 0);
  for (int kt = 0; kt < NKT; ++kt) {
    const int p = kt & 1;
    if (kt + 1 < NKT) {
      STAGE_QKV(p ^ 1, kt + 1);
      asm volatile("s_waitcnt vmcnt(4)" ::: "memory");
    } else {
      asm volatile("s_waitcnt vmcnt(0)" ::: "memory");
    }
    __builtin_amdgcn_s_barrier();

    f16x8 af[4], bf[4];
#pragma unroll
    for (int i = 0; i < 4; ++i) af[i] = *(const f16x8*)&aT[p][(wr * 64 + i * 16 + lr) * BK + hi * 8];
#pragma unroll
    for (int j = 0; j < 4; ++j) bf[j] = *(const f16x8*)&bT[p][(wc * 64 + j * 16 + lr) * BK + hi * 8];
    __builtin_amdgcn_s_setprio(1);
#pragma unroll
    for (int i = 0; i < 4; ++i)
#pragma unroll
      for (int j = 0; j < 4; ++j)
        acc[i][j] = __builtin_amdgcn_mfma_f32_16x16x32_f16(af[i], bf[j], acc[i][j], 0, 0, 0);
    __builtin_amdgcn_s_setprio(0);
    __builtin_amdgcn_s_barrier();
  }

  const float scale = (z == 0) ? ALPHA : 1.0f;
#pragma unroll
  for (int i = 0; i < 4; ++i) {
#pragma unroll
    for (int j = 0; j < 4; ++j) {
      const int row = mb + wr * 64 + i * 16 + hi * 4;
      const int col = nb + wc * 64 + j * 16 + lr;
      const float bv = bias[col];
      const int hh = col >> 6, dd = col & 63;
      if (z == 2) {
        const int bb = row >> 11, l = row & 2047;
        f16x4 v4;
#pragma unroll
        for (int r = 0; r < 4; ++r) v4[r] = (f16)(acc[i][j][r] + bv);
        *(f16x4*)(vo + ((((size_t)bb * 16 + hh) * 64 + dd) * 2048 + l)) = v4;
      } else {
        f16* o = z ? ko : qo;
#pragma unroll
        for (int r = 0; r < 4; ++r) {
          const int m2 = row + r;
          const int bb = m2 >> 11, l = m2 & 2047;
          o[((((size_t)bb * 16 + hh) * 2048 + l) * 64) + dd] = (f16)((acc[i][j][r] + bv) * scale);
        }
      }
    }
  }
}

// ---------------------------------------------------------------------------
// Output projection: 64(M)x128(N) tile, 2-phase pipeline, XCD-chunked swizzle.
// ---------------------------------------------------------------------------
__global__ __launch_bounds__(256) void gemm_o(const f16* __restrict__ A,
                                              const f16* __restrict__ W,
                                              const float* __restrict__ bias,
                                              float* __restrict__ out) {
  constexpr int K = 1024, N = 1024, BK = 32, NKT = K / BK;
  __shared__ f16 aT[2][64 * BK];
  __shared__ f16 bT[2][128 * BK];
  const int rid = (blockIdx.x & 7) * 64 + (blockIdx.x >> 3);
  const int tid = threadIdx.x, wid = tid >> 6, lane = tid & 63;
  const int lr = lane & 15, hi = lane >> 4;
  const int mb = (rid >> 3) * 64, nb = (rid & 7) * 128;
  const int wr = wid >> 1, wc = wid & 1;
  f32x4 acc[2][4] = {};
  const int ra = tid >> 2, sa = tid & 3;
  const int rb1 = (256 + tid) >> 2, sb1 = (256 + tid) & 3;

#define STAGE_O(bb, kt)                                                                     \
  do {                                                                                      \
    const int kb_ = (kt) * BK;                                                              \
    LDS_LOAD16(A + (size_t)(mb + ra) * K + kb_ + sa * 8, (char*)aT[bb] + wid * 1024);       \
    LDS_LOAD16(W + (size_t)(nb + ra) * K + kb_ + sa * 8, (char*)bT[bb] + wid * 1024);       \
    LDS_LOAD16(W + (size_t)(nb + rb1) * K + kb_ + sb1 * 8, (char*)bT[bb] + 4096 + wid * 1024);\
  } while (0)

  STAGE_O(0, 0);
  for (int kt = 0; kt < NKT; ++kt) {
    const int p = kt & 1;
    if (kt + 1 < NKT) {
      STAGE_O(p ^ 1, kt + 1);
      asm volatile("s_waitcnt vmcnt(3)" ::: "memory");
    } else {
      asm volatile("s_waitcnt vmcnt(0)" ::: "memory");
    }
    __builtin_amdgcn_s_barrier();
    f16x8 af[2], bf[4];
#pragma unroll
    for (int i = 0; i < 2; ++i) af[i] = *(const f16x8*)&aT[p][(wr * 32 + i * 16 + lr) * BK + hi * 8];
#pragma unroll
    for (int j = 0; j < 4; ++j) bf[j] = *(const f16x8*)&bT[p][(wc * 64 + j * 16 + lr) * BK + hi * 8];
    __builtin_amdgcn_s_setprio(1);
#pragma unroll
    for (int i = 0; i < 2; ++i)
#pragma unroll
      for (int j = 0; j < 4; ++j)
        acc[i][j] = __builtin_amdgcn_mfma_f32_16x16x32_f16(af[i], bf[j], acc[i][j], 0, 0, 0);
    __builtin_amdgcn_s_setprio(0);
    __builtin_amdgcn_s_barrier();
  }
#pragma unroll
  for (int i = 0; i < 2; ++i)
#pragma unroll
    for (int j = 0; j < 4; ++j) {
      const int col = nb + wc * 64 + j * 16 + lr;
      const float bv = bias[col];
#pragma unroll
      for (int r = 0; r < 4; ++r)
        out[(size_t)(mb + wr * 32 + i * 16 + hi * 4 + r) * N + col] = acc[i][j][r] + bv;
    }
}

// ---------------------------------------------------------------------------
// Flash attention v6: 32x32x16 MFMA, 4 waves x 32 q (128 q/block), grid 512.
// Halves LDS bytes per FLOP vs 16x16x32.  Swapped QK^T: S^T[kv][q] via
// mfma(K,Q); D-layout col=lane&31 (= q), rows=(reg&3)+8*(reg>>2)+4*(lane>>5)
// -> each lane holds 32 P-values of ONE q: lsum is in-lane adds, epilogue
// divisor is a per-lane scalar.  P->PV B-fragments need only 2
// permlane32_swap per k-step.  KV tiles of 64, dbuf staging, 1 barrier/tile.
// p = exp2(score*log2e); Q pre-scaled by ALPHA; mask all-ones fast path.
// ---------------------------------------------------------------------------
__global__ __launch_bounds__(256, 2) void attn32q(const f16* __restrict__ Qh,
                                                  const f16* __restrict__ Kh,
                                                  const f16* __restrict__ Vt,
                                                  const int* __restrict__ mask,
                                                  f16* __restrict__ Oa) {
  constexpr int L = 2048, HD = 64, H = 16, NT = L / 64;
  // [parity][ K(8KB) | V(8KB) ] = 32 KB
  __shared__ __align__(16) char ldsb[32768];

  const int tid = threadIdx.x, w = tid >> 6, lane = tid & 63;
  const int q32 = lane & 31, h5 = lane >> 5, x7 = lane & 7;

  // XCD remap: 512 blocks = 8 xcd x (16 qb x 4 heads)
  const int bid = blockIdx.x;
  const int head = (bid & 7) * 4 + (bid >> 7);
  const int qb = (bid >> 3) & 15;
  const int b = head >> 4, h = head & 15;
  const int qr0 = qb * 128 + w * 32;

  const f16* Qb = Qh + (size_t)head * L * HD;
  const f16* Kb = Kh + (size_t)head * L * HD;
  const f16* Vb = Vt + (size_t)head * HD * L;
  const int* mrow = mask + b * L;

  // whole-row mask scan (wave-uniform fast path)
  int mred = 1;
  {
    const int4* m4 = (const int4*)mrow;
#pragma unroll
    for (int j = 0; j < 8; ++j) {
      int4 v = m4[lane + j * 64];
      mred &= v.x & v.y & v.z & v.w;
    }
  }
  const bool allm = __all(mred == 1);

  // staging (identical family to v5): wave w stages K rows [w*16,w*16+16) and
  // V^T rows likewise; source chunk pre-swizzled by row&7, LDS dest linear.
  const int srow = lane >> 3;
  const int schk = (lane & 7) ^ srow;

#define STAGE32(bb, kt)                                                                     \
  _Pragma("unroll") for (int c = 0; c < 2; ++c) {                                           \
    LDS_LOAD16(Kb + (size_t)((kt) * 64 + w * 16 + c * 8 + srow) * HD + schk * 8,            \
               ldsb + (bb) * 16384 + w * 2048 + c * 1024);                                  \
    LDS_LOAD16(Vb + (size_t)(w * 16 + c * 8 + srow) * L + (kt) * 64 + schk * 8,             \
               ldsb + (bb) * 16384 + 8192 + w * 2048 + c * 1024);                           \
  }

  // read bases: row = (t*32 + q32), chunk (2s+h5)^(row&7); row&7 == x7
  const char* kb[4];
#pragma unroll
  for (int s = 0; s < 4; ++s)
    kb[s] = ldsb + q32 * 128 + (((2 * s + h5) ^ x7) * 16);

  // Q fragments (B-operand): lane holds col q=q32, k = s*16 + h5*8 + e
  f16x8 qf[4];
#pragma unroll
  for (int s = 0; s < 4; ++s)
    qf[s] = *(const f16x8*)&Qb[(size_t)(qr0 + q32) * HD + s * 16 + h5 * 8];

  f32x16 oacc[2] = {};
  float lsum = 0.f;
  const f32x16 zacc = {};

  int4 mvA[2][4], mvB[2][4];
  if (!allm) {
#pragma unroll
    for (int t = 0; t < 2; ++t)
#pragma unroll
      for (int g = 0; g < 4; ++g) mvA[t][g] = *(const int4*)&mrow[t * 32 + 4 * h5 + 8 * g];
  }
  STAGE32(0, 0);

#define ATTN_I32(kt, P, MVR, MVL)                                                           \
  do {                                                                                      \
    asm volatile("s_waitcnt vmcnt(0)" ::: "memory");                                        \
    __builtin_amdgcn_s_barrier();                                                           \
    if ((kt) + 1 < NT) {                                                                    \
      if (!allm) {                                                                          \
        _Pragma("unroll") for (int t = 0; t < 2; ++t)                                       \
            _Pragma("unroll") for (int g = 0; g < 4; ++g)                                   \
                MVL[t][g] = *(const int4*)&mrow[((kt) + 1) * 64 + t * 32 + 4 * h5 + 8 * g]; \
      }                                                                                     \
      STAGE32((P) ^ 1, (kt) + 1);                                                           \
    }                                                                                       \
    f32x16 st[2];                                                                           \
    __builtin_amdgcn_s_setprio(1);                                                          \
    _Pragma("unroll") for (int t = 0; t < 2; ++t) {                                         \
      f32x16 a_ = zacc;                                                                     \
      _Pragma("unroll") for (int s = 0; s < 4; ++s) {                                       \
        f16x8 kf = *(const f16x8*)(kb[s] + (P) * 16384 + t * 4096);                         \
        a_ = __builtin_amdgcn_mfma_f32_32x32x16_f16(kf, qf[s], a_, 0, 0, 0);                \
      }                                                                                     \
      st[t] = a_;                                                                           \
    }                                                                                       \
    __builtin_amdgcn_s_setprio(0);                                                          \
    int u[2][8];                                                                            \
    _Pragma("unroll") for (int t = 0; t < 2; ++t)                                           \
        _Pragma("unroll") for (int j = 0; j < 8; ++j) {                                     \
      float e0, e1;                                                                         \
      if (allm) {                                                                           \
        e0 = __builtin_amdgcn_exp2f(st[t][2 * j]);                                          \
        e1 = __builtin_amdgcn_exp2f(st[t][2 * j + 1]);                                      \
      } else {                                                                              \
        const int r0_ = 2 * j, r1_ = 2 * j + 1;                                             \
        int m0 = ((const int*)&MVR[t][r0_ >> 2])[r0_ & 3];                                  \
        int m1 = ((const int*)&MVR[t][r1_ >> 2])[r1_ & 3];                                  \
        e0 = __builtin_amdgcn_exp2f(m0 ? st[t][r0_] : MASKVAL);                             \
        e1 = __builtin_amdgcn_exp2f(m1 ? st[t][r1_] : MASKVAL);                             \
      }                                                                                     \
      lsum += e0 + e1;                                                                      \
      u[t][j] = __builtin_bit_cast(int, __builtin_amdgcn_cvt_pkrtz(e0, e1));                \
    }                                                                                       \
    __builtin_amdgcn_s_setprio(1);                                                          \
    _Pragma("unroll") for (int t = 0; t < 2; ++t)                                           \
        _Pragma("unroll") for (int sg = 0; sg < 2; ++sg) {                                  \
      int X0 = u[t][sg * 4 + 0], Y0 = u[t][sg * 4 + 2];                                     \
      int X1 = u[t][sg * 4 + 1], Y1 = u[t][sg * 4 + 3];                                     \
      asm("v_permlane32_swap_b32 %0, %1" : "+v"(X0), "+v"(Y0));                             \
      asm("v_permlane32_swap_b32 %0, %1" : "+v"(X1), "+v"(Y1));                             \
      i32x4 cc = {X0, X1, Y0, Y1};                                                          \
      f16x8 pfr = __builtin_bit_cast(f16x8, cc);                                            \
      const int sp = t * 2 + sg;                                                            \
      _Pragma("unroll") for (int dt = 0; dt < 2; ++dt) {                                    \
        f16x8 vf = *(const f16x8*)(kb[sp] + (P) * 16384 + 8192 + dt * 4096);                \
        oacc[dt] = __builtin_amdgcn_mfma_f32_32x32x16_f16(vf, pfr, oacc[dt], 0, 0, 0);      \
      }                                                                                     \
    }                                                                                       \
    __builtin_amdgcn_s_setprio(0);                                                          \
  } while (0)

  for (int kt = 0; kt < NT; kt += 2) {
    ATTN_I32(kt, 0, mvA, mvB);
    ATTN_I32(kt + 1, 1, mvB, mvA);
  }

  // epilogue: lanes l and l+32 hold partial sums for the same q = q32
  lsum += __shfl_xor(lsum, 32);
  const float rinv = 1.0f / lsum;
#pragma unroll
  for (int dt = 0; dt < 2; ++dt)
#pragma unroll
    for (int g = 0; g < 4; ++g) {
      f16x4 v4;
#pragma unroll
      for (int c = 0; c < 4; ++c) v4[c] = (f16)(oacc[dt][g * 4 + c] * rinv);
      const int d0 = dt * 32 + 4 * h5 + 8 * g;
      *(f16x4*)&Oa[(((size_t)b * L + qr0 + q32) * H + h) * HD + d0] = v4;
    }
}

// ---------------------------------------------------------------------------
extern "C" void kernel_launch(void* const* d_in, const int* in_sizes, int n_in,
                              void* d_out, int out_size, void* d_ws, size_t ws_size,
                              hipStream_t stream) {
  const float* x  = (const float*)d_in[0];
  const int* mask = (const int*)d_in[1];
  const float* Wq = (const float*)d_in[2];
  const float* bq = (const float*)d_in[3];
  const float* Wk = (const float*)d_in[4];
  const float* bk = (const float*)d_in[5];
  const float* Wv = (const float*)d_in[6];
  const float* bv = (const float*)d_in[7];
  const float* Wo = (const float*)d_in[8];
  const float* bo = (const float*)d_in[9];
  float* out = (float*)d_out;

  char* ws = (char*)d_ws;
  const size_t MB = 1u << 20;
  f16* xh  = (f16*)(ws);             // 4096x1024  (8 MB)
  f16* wqh = (f16*)(ws + 8 * MB);    // 1024x1024  (2 MB)
  f16* wkh = (f16*)(ws + 10 * MB);
  f16* wvh = (f16*)(ws + 12 * MB);
  f16* woh = (f16*)(ws + 14 * MB);
  f16* qh  = (f16*)(ws + 16 * MB);   // [2][16][2048][64], pre-scaled by ALPHA
  f16* kh  = (f16*)(ws + 24 * MB);   // [2][16][2048][64]
  f16* vth = (f16*)(ws + 32 * MB);   // [2][16][64][2048]
  f16* oah = (f16*)(ws + 40 * MB);   // [2][2048][16][64] = [4096][1024]

  conv_all<<<4096, 256, 0, stream>>>(x, Wq, Wk, Wv, Wo, xh, wqh, wkh, wvh, woh);

  gemm_qkv<<<768, 256, 0, stream>>>(xh, wqh, wkh, wvh, bq, bk, bv, qh, kh, vth);

  attn32q<<<dim3(512), 256, 0, stream>>>(qh, kh, vth, mask, oah);

  gemm_o<<<512, 256, 0, stream>>>(oah, woh, bo, out);
}